// Round 1
// baseline (21127.193 us; speedup 1.0000x reference)
//
#include <hip/hip_runtime.h>

// GraphLSTM: S=32 steps, N=65536 nodes.
// 3 kernels per step: k_graph (graph LSTM + partial sums + p=gh@w_graph),
// k_reduce (sum partials -> sum_p), k_cell (cell LSTM + outputs).
// States live in the d_out slots (ch,cc,gh,gc) so finals are in place.

#define Sx    32
#define Nx    65536
#define INx   2
#define DYNx  32
#define GEMBx 32
#define GHx   64
#define MATx  32
#define CHx   64
#define CEx   64
#define OUTx  5
#define TPB   256
#define NBLK  (Nx / TPB)   // 256 blocks

__device__ __forceinline__ float sigm(float x) {
    return __frcp_rn(1.f + __expf(-x));
}
__device__ __forceinline__ float tanh_fast(float x) {
    // tanh(x) = 1 - 2/(exp(2x)+1); inf-safe at both ends.
    return fmaf(-2.f, __frcp_rn(1.f + __expf(2.f * x)), 1.f);
}

__global__ __launch_bounds__(TPB) void k_graph(
    const float* __restrict__ frame,                 // [N][2] (input_data + t*N*2)
    float* __restrict__ gh, float* __restrict__ gc,  // [N][64] state (in d_out)
    const float* __restrict__ Wge, const float* __restrict__ bge,  // [32][2],[32]
    const float* __restrict__ Wih, const float* __restrict__ Whh,  // [256][32],[256][64]
    const float* __restrict__ bih, const float* __restrict__ bhh,  // [256],[256]
    const float* __restrict__ wgr,                   // w_graph [64][32]
    float* __restrict__ p,                           // [N][32]  (ws)
    float* __restrict__ partials)                    // [NBLK][64] (ws)
{
    const int n = blockIdx.x * TPB + threadIdx.x;
    const int lane = threadIdx.x & 63;
    const float f0 = frame[2 * n], f1 = frame[2 * n + 1];

    // gemb = relu(frame @ W_gemb^T + b)
    float ge[GEMBx];
#pragma unroll
    for (int j = 0; j < GEMBx; ++j) {
        float v = fmaf(f1, Wge[2 * j + 1], fmaf(f0, Wge[2 * j], bge[j]));
        ge[j] = fmaxf(v, 0.f);
    }
    // old h in registers (in-place global update below is safe)
    float h[GHx];
#pragma unroll
    for (int k = 0; k < GHx; ++k) h[k] = gh[(size_t)n * GHx + k];

    float pacc[MATx];
#pragma unroll
    for (int j = 0; j < MATx; ++j) pacc[j] = 0.f;

    float mysum = 0.f;  // lane l accumulates wave-sum of h2[l]

#pragma unroll 2
    for (int d = 0; d < GHx; ++d) {
        float ai = bih[d]       + bhh[d];
        float af = bih[64 + d]  + bhh[64 + d];
        float ag = bih[128 + d] + bhh[128 + d];
        float ao = bih[192 + d] + bhh[192 + d];
#pragma unroll
        for (int k = 0; k < GEMBx; ++k) {
            const float x = ge[k];
            ai = fmaf(Wih[d * GEMBx + k], x, ai);
            af = fmaf(Wih[(64 + d) * GEMBx + k], x, af);
            ag = fmaf(Wih[(128 + d) * GEMBx + k], x, ag);
            ao = fmaf(Wih[(192 + d) * GEMBx + k], x, ao);
        }
#pragma unroll
        for (int k = 0; k < GHx; ++k) {
            const float x = h[k];
            ai = fmaf(Whh[d * GHx + k], x, ai);
            af = fmaf(Whh[(64 + d) * GHx + k], x, af);
            ag = fmaf(Whh[(128 + d) * GHx + k], x, ag);
            ao = fmaf(Whh[(192 + d) * GHx + k], x, ao);
        }
        const float c2 = fmaf(sigm(af), gc[(size_t)n * GHx + d], sigm(ai) * tanh_fast(ag));
        gc[(size_t)n * GHx + d] = c2;
        const float h2 = sigm(ao) * tanh_fast(c2);
        gh[(size_t)n * GHx + d] = h2;
        // p = h2 @ w_graph (incremental)
#pragma unroll
        for (int j = 0; j < MATx; ++j) pacc[j] = fmaf(h2, wgr[d * MATx + j], pacc[j]);
        // wave butterfly sum of h2 across 64 nodes; lane d keeps dim d
        float r = h2;
        r += __shfl_xor(r, 1);  r += __shfl_xor(r, 2);  r += __shfl_xor(r, 4);
        r += __shfl_xor(r, 8);  r += __shfl_xor(r, 16); r += __shfl_xor(r, 32);
        if (lane == d) mysum = r;
    }
#pragma unroll
    for (int j = 0; j < MATx; ++j) p[(size_t)n * MATx + j] = pacc[j];

    __shared__ float ls[TPB / 64][64];
    ls[threadIdx.x >> 6][lane] = mysum;
    __syncthreads();
    if (threadIdx.x < 64) {
        float a = ls[0][threadIdx.x] + ls[1][threadIdx.x] +
                  ls[2][threadIdx.x] + ls[3][threadIdx.x];
        partials[blockIdx.x * 64 + threadIdx.x] = a;
    }
}

__global__ __launch_bounds__(64) void k_reduce(
    const float* __restrict__ partials,   // [NBLK][64]
    const float* __restrict__ wgr,        // [64][32]
    float* __restrict__ sum_p)            // [32]
{
    __shared__ float s[GHx];
    const int d = threadIdx.x;
    float acc = 0.f;
    for (int b = 0; b < NBLK; ++b) acc += partials[b * GHx + d];
    s[d] = acc;
    __syncthreads();
    if (d < MATx) {
        float a = 0.f;
#pragma unroll
        for (int k = 0; k < GHx; ++k) a = fmaf(s[k], wgr[k * MATx + d], a);
        sum_p[d] = a;
    }
}

__global__ __launch_bounds__(TPB) void k_cell(
    const float* __restrict__ frame,                 // [N][2]
    const float* __restrict__ p,                     // [N][32]
    const float* __restrict__ sum_p,                 // [32]
    float* __restrict__ ch, float* __restrict__ cc,  // [N][64] state (in d_out)
    const float* __restrict__ Wdy, const float* __restrict__ bdy,  // [32][2],[32]
    const float* __restrict__ Wih, const float* __restrict__ Whh,  // [256][64],[256][64]
    const float* __restrict__ bih, const float* __restrict__ bhh,
    const float* __restrict__ Wo,  const float* __restrict__ bo,   // [5][64],[5]
    float* __restrict__ outp)                        // [N][5] (d_out + t*N*5)
{
    const int n = blockIdx.x * TPB + threadIdx.x;
    const float f0 = frame[2 * n], f1 = frame[2 * n + 1];

    // cell_emb = [ relu(frame@W_dyn^T+b) ; sum_p - p_self ]
    float xe[CEx];
#pragma unroll
    for (int j = 0; j < DYNx; ++j) {
        float v = fmaf(f1, Wdy[2 * j + 1], fmaf(f0, Wdy[2 * j], bdy[j]));
        xe[j] = fmaxf(v, 0.f);
    }
#pragma unroll
    for (int j = 0; j < MATx; ++j)
        xe[DYNx + j] = sum_p[j] - p[(size_t)n * MATx + j];

    float h[CHx];
#pragma unroll
    for (int k = 0; k < CHx; ++k) h[k] = ch[(size_t)n * CHx + k];

    float oacc[OUTx];
#pragma unroll
    for (int o = 0; o < OUTx; ++o) oacc[o] = bo[o];

#pragma unroll 2
    for (int d = 0; d < CHx; ++d) {
        float ai = bih[d]       + bhh[d];
        float af = bih[64 + d]  + bhh[64 + d];
        float ag = bih[128 + d] + bhh[128 + d];
        float ao = bih[192 + d] + bhh[192 + d];
#pragma unroll
        for (int k = 0; k < CEx; ++k) {
            const float x = xe[k];
            ai = fmaf(Wih[d * CEx + k], x, ai);
            af = fmaf(Wih[(64 + d) * CEx + k], x, af);
            ag = fmaf(Wih[(128 + d) * CEx + k], x, ag);
            ao = fmaf(Wih[(192 + d) * CEx + k], x, ao);
        }
#pragma unroll
        for (int k = 0; k < CHx; ++k) {
            const float x = h[k];
            ai = fmaf(Whh[d * CHx + k], x, ai);
            af = fmaf(Whh[(64 + d) * CHx + k], x, af);
            ag = fmaf(Whh[(128 + d) * CHx + k], x, ag);
            ao = fmaf(Whh[(192 + d) * CHx + k], x, ao);
        }
        const float c2 = fmaf(sigm(af), cc[(size_t)n * CHx + d], sigm(ai) * tanh_fast(ag));
        cc[(size_t)n * CHx + d] = c2;
        const float h2 = sigm(ao) * tanh_fast(c2);
        ch[(size_t)n * CHx + d] = h2;
#pragma unroll
        for (int o = 0; o < OUTx; ++o) oacc[o] = fmaf(h2, Wo[o * CHx + d], oacc[o]);
    }
#pragma unroll
    for (int o = 0; o < OUTx; ++o) outp[(size_t)n * OUTx + o] = oacc[o];
}

extern "C" void kernel_launch(void* const* d_in, const int* in_sizes, int n_in,
                              void* d_out, int out_size, void* d_ws, size_t ws_size,
                              hipStream_t stream) {
    const float* input   = (const float*)d_in[0];   // [S][N][2]
    const float* cell_h0 = (const float*)d_in[1];
    const float* cell_c0 = (const float*)d_in[2];
    const float* graph_h0= (const float*)d_in[3];
    const float* graph_c0= (const float*)d_in[4];
    const float* W_dyn   = (const float*)d_in[5];
    const float* b_dyn   = (const float*)d_in[6];
    const float* W_gemb  = (const float*)d_in[7];
    const float* b_gemb  = (const float*)d_in[8];
    const float* Wih_g   = (const float*)d_in[9];
    const float* Whh_g   = (const float*)d_in[10];
    const float* bih_g   = (const float*)d_in[11];
    const float* bhh_g   = (const float*)d_in[12];
    const float* w_graph = (const float*)d_in[13];
    const float* Wih_c   = (const float*)d_in[14];
    const float* Whh_c   = (const float*)d_in[15];
    const float* bih_c   = (const float*)d_in[16];
    const float* bhh_c   = (const float*)d_in[17];
    const float* W_out   = (const float*)d_in[18];
    const float* b_out   = (const float*)d_in[19];

    float* out0 = (float*)d_out;                        // [S][N][5]
    float* ch = out0 + (size_t)Sx * Nx * OUTx;          // [N][64]
    float* cc = ch + (size_t)Nx * CHx;
    float* gh = cc + (size_t)Nx * CHx;
    float* gc = gh + (size_t)Nx * GHx;

    float* p        = (float*)d_ws;                     // [N][32]
    float* partials = p + (size_t)Nx * MATx;            // [NBLK][64]
    float* sum_p    = partials + (size_t)NBLK * GHx;    // [32]

    // init live states from provided initial states
    hipMemcpyAsync(ch, cell_h0,  (size_t)Nx * CHx * sizeof(float), hipMemcpyDeviceToDevice, stream);
    hipMemcpyAsync(cc, cell_c0,  (size_t)Nx * CHx * sizeof(float), hipMemcpyDeviceToDevice, stream);
    hipMemcpyAsync(gh, graph_h0, (size_t)Nx * GHx * sizeof(float), hipMemcpyDeviceToDevice, stream);
    hipMemcpyAsync(gc, graph_c0, (size_t)Nx * GHx * sizeof(float), hipMemcpyDeviceToDevice, stream);

    for (int t = 0; t < Sx; ++t) {
        const float* frame = input + (size_t)t * Nx * INx;
        k_graph<<<NBLK, TPB, 0, stream>>>(frame, gh, gc, W_gemb, b_gemb,
                                          Wih_g, Whh_g, bih_g, bhh_g,
                                          w_graph, p, partials);
        k_reduce<<<1, 64, 0, stream>>>(partials, w_graph, sum_p);
        k_cell<<<NBLK, TPB, 0, stream>>>(frame, p, sum_p, ch, cc,
                                         W_dyn, b_dyn, Wih_c, Whh_c, bih_c, bhh_c,
                                         W_out, b_out,
                                         out0 + (size_t)t * Nx * OUTx);
    }
}

// Round 2
// 2298.638 us; speedup vs baseline: 9.1912x; 9.1912x over previous
//
#include <hip/hip_runtime.h>

// GraphLSTM MFMA version. S=32 steps, N=65536 nodes.
// Per step: k_graph (bf16 MFMA gates [N,96]@[96,256] + LSTM pointwise + block
// sums of gh2), k_reduce (S=sum gh2 -> step bias for cell gates, f32),
// k_cell (bf16 MFMA gates [N,160]@[160,256], K = [dyn | gh2 | ch], with the
// graph_feat contribution folded: per-node -gh2@Wfold in K, common S@Wfold in
// the step bias). h-states carried in bf16 (ws); c-states f32 (d_out slots).

#define Sx    32
#define Nx    65536
#define DYNx  32
#define GHx   64
#define MATx  32
#define CHx   64
#define OUTx  5
#define NPB   64              // nodes per block (4 waves x 16)
#define GB    (Nx / NPB)      // 1024 blocks
#define KG    96              // graph gates K: [gemb(32) | gh(64)]
#define KC    160             // cell gates K:  [dyn(32) | gh2(64) | ch(64)]

typedef __attribute__((ext_vector_type(4))) float f32x4;
typedef __attribute__((ext_vector_type(8))) short bf16x8;
typedef unsigned short ushort;
typedef unsigned int uint;

__device__ __forceinline__ float sigm(float x) {
    return __frcp_rn(1.f + __expf(-x));
}
__device__ __forceinline__ float tanh_fast(float x) {
    return fmaf(-2.f, __frcp_rn(1.f + __expf(2.f * x)), 1.f);
}
__device__ __forceinline__ ushort f2b(float x) {
    uint u = __float_as_uint(x);
    u += 0x7fffu + ((u >> 16) & 1u);   // RNE
    return (ushort)(u >> 16);
}

// ---------------- weight prep (once per launch) ----------------
__global__ __launch_bounds__(256) void k_prep(
    const float* __restrict__ Wih_g, const float* __restrict__ Whh_g,
    const float* __restrict__ bih_g, const float* __restrict__ bhh_g,
    const float* __restrict__ wgr,
    const float* __restrict__ Wih_c, const float* __restrict__ Whh_c,
    const float* __restrict__ bih_c, const float* __restrict__ bhh_c,
    ushort* __restrict__ Wg, ushort* __restrict__ Wc,
    float* __restrict__ bsum_g, float* __restrict__ bC0)
{
    const int tid = threadIdx.x;
    for (int idx = tid; idx < 256 * KG; idx += 256) {
        int col = idx / KG, k = idx % KG;
        float v = (k < 32) ? Wih_g[col * 32 + k] : Whh_g[col * 64 + (k - 32)];
        Wg[idx] = f2b(v);
    }
    for (int idx = tid; idx < 256 * KC; idx += 256) {
        int col = idx / KC, k = idx % KC;
        float v;
        if (k < 32) v = Wih_c[col * 64 + k];
        else if (k < 96) {
            int d = k - 32; float a = 0.f;
            for (int j = 0; j < 32; ++j)
                a = fmaf(wgr[d * 32 + j], Wih_c[col * 64 + 32 + j], a);
            v = -a;   // per-node part of loo is (-gh2)
        } else v = Whh_c[col * 64 + (k - 96)];
        Wc[idx] = f2b(v);
    }
    if (tid < 256) {
        bsum_g[tid] = bih_g[tid] + bhh_g[tid];
        bC0[tid]    = bih_c[tid] + bhh_c[tid];
    }
}

__global__ __launch_bounds__(256) void k_init(
    const float* __restrict__ gh0, const float* __restrict__ ch0,
    ushort* __restrict__ ghb, ushort* __restrict__ chb)
{
    const int i = blockIdx.x * 256 + threadIdx.x;
    ghb[i] = f2b(gh0[i]);
    chb[i] = f2b(ch0[i]);
}

// ---------------- graph LSTM step ----------------
__global__ __launch_bounds__(256) void k_graph(
    const float* __restrict__ frame,               // [N][2]
    const float* __restrict__ Wge, const float* __restrict__ bge,  // [32][2],[32]
    const ushort* __restrict__ Wg,                 // [256][96] bf16
    const float* __restrict__ bsum_g,              // [256]
    float* __restrict__ gc,                        // [N][64] f32 live state
    ushort* __restrict__ ghb,                      // [N][64] bf16 live state
    float* __restrict__ ghf,                       // [N][64] f32 (written iff last)
    float* __restrict__ partials,                  // [GB][64]
    int last)
{
    const int wave = threadIdx.x >> 6, lane = threadIdx.x & 63;
    const int c = lane & 15, g4 = lane >> 4;
    const int nbase = blockIdx.x * NPB + wave * 16;

    // ---- A fragments (rows = nodes nbase+c) ----
    const int na = nbase + c;
    const float f0 = frame[2 * na], f1 = frame[2 * na + 1];
    bf16x8 a0, a1, a2;
    {
#pragma unroll
        for (int j = 0; j < 8; ++j) {
            int k = g4 * 8 + j;
            float v = fmaf(f1, Wge[2 * k + 1], fmaf(f0, Wge[2 * k], bge[k]));
            a0[j] = (short)f2b(fmaxf(v, 0.f));
        }
        a1 = *(const bf16x8*)(ghb + na * 64 + g4 * 8);
        a2 = *(const bf16x8*)(ghb + na * 64 + 32 + g4 * 8);
    }

    float hsq[4];
#pragma unroll
    for (int q = 0; q < 4; ++q) {
        f32x4 acc[4];
#pragma unroll
        for (int g = 0; g < 4; ++g) {
            acc[g] = (f32x4){0.f, 0.f, 0.f, 0.f};
            const int colb = 16 * (4 * g + q);
            const ushort* wp = Wg + (colb + c) * KG + g4 * 8;
            bf16x8 b0 = *(const bf16x8*)(wp);
            bf16x8 b1 = *(const bf16x8*)(wp + 32);
            bf16x8 b2 = *(const bf16x8*)(wp + 64);
            acc[g] = __builtin_amdgcn_mfma_f32_16x16x32_bf16(a0, b0, acc[g], 0, 0, 0);
            acc[g] = __builtin_amdgcn_mfma_f32_16x16x32_bf16(a1, b1, acc[g], 0, 0, 0);
            acc[g] = __builtin_amdgcn_mfma_f32_16x16x32_bf16(a2, b2, acc[g], 0, 0, 0);
        }
        // pointwise LSTM for dims d=16q+c, rows 4*g4+r
        const int d = 16 * q + c;
        const float bi = bsum_g[d], bf = bsum_g[64 + d],
                    bg = bsum_g[128 + d], bo = bsum_g[192 + d];
        float s_r = 0.f;
#pragma unroll
        for (int r = 0; r < 4; ++r) {
            const int n = nbase + 4 * g4 + r;
            const float ai = acc[0][r] + bi, af = acc[1][r] + bf,
                        ag = acc[2][r] + bg, ao = acc[3][r] + bo;
            const float cp = gc[n * 64 + d];
            const float c2 = fmaf(sigm(af), cp, sigm(ai) * tanh_fast(ag));
            gc[n * 64 + d] = c2;
            const float h2 = sigm(ao) * tanh_fast(c2);
            ghb[n * 64 + d] = f2b(h2);
            if (last) ghf[n * 64 + d] = h2;
            s_r += h2;
        }
        hsq[q] = s_r;
    }
    // reduce across g4 groups (rows) -> per-wave dim sums
#pragma unroll
    for (int q = 0; q < 4; ++q) {
        float v = hsq[q];
        v += __shfl_xor(v, 16);
        v += __shfl_xor(v, 32);
        hsq[q] = v;
    }
    __shared__ float wsum[4][64];
    if (g4 == 0) {
#pragma unroll
        for (int q = 0; q < 4; ++q) wsum[wave][16 * q + c] = hsq[q];
    }
    __syncthreads();
    if (threadIdx.x < 64) {
        partials[blockIdx.x * 64 + threadIdx.x] =
            wsum[0][threadIdx.x] + wsum[1][threadIdx.x] +
            wsum[2][threadIdx.x] + wsum[3][threadIdx.x];
    }
}

// ---------------- per-step reduce: S, then cell-gate step bias ----------------
__global__ __launch_bounds__(256) void k_reduce(
    const float* __restrict__ partials,   // [GB][64]
    const float* __restrict__ wgr,        // [64][32]
    const float* __restrict__ Wih_c,      // [256][64]
    const float* __restrict__ bC0,        // [256]
    float* __restrict__ bias_c)           // [256]
{
    __shared__ float ps[4][64];
    __shared__ float S[64];
    __shared__ float gsf[32];
    const int tid = threadIdx.x;
    const int d = tid & 63, g = tid >> 6;
    float acc = 0.f;
    for (int b = g * (GB / 4); b < (g + 1) * (GB / 4); ++b)
        acc += partials[b * 64 + d];
    ps[g][d] = acc;
    __syncthreads();
    if (tid < 64) S[tid] = ps[0][tid] + ps[1][tid] + ps[2][tid] + ps[3][tid];
    __syncthreads();
    if (tid < 32) {
        float a = 0.f;
#pragma unroll
        for (int k = 0; k < 64; ++k) a = fmaf(S[k], wgr[k * 32 + tid], a);
        gsf[tid] = a;
    }
    __syncthreads();
    float b = bC0[tid];
#pragma unroll
    for (int j = 0; j < 32; ++j) b = fmaf(gsf[j], Wih_c[tid * 64 + 32 + j], b);
    bias_c[tid] = b;
}

// ---------------- cell LSTM step + outputs ----------------
__global__ __launch_bounds__(256) void k_cell(
    const float* __restrict__ frame,               // [N][2]
    const float* __restrict__ Wdy, const float* __restrict__ bdy,  // [32][2],[32]
    const ushort* __restrict__ Wc,                 // [256][160] bf16
    const float* __restrict__ bias_c,              // [256] (incl. S-fold)
    const ushort* __restrict__ ghb,                // [N][64] bf16 (gh2 of step t)
    float* __restrict__ cc,                        // [N][64] f32 live state
    ushort* __restrict__ chb,                      // [N][64] bf16 live state
    float* __restrict__ chf,                       // [N][64] f32 (iff last)
    const float* __restrict__ Wout, const float* __restrict__ bo5, // [5][64],[5]
    float* __restrict__ outp,                      // [N][5]
    int last)
{
    const int wave = threadIdx.x >> 6, lane = threadIdx.x & 63;
    const int c = lane & 15, g4 = lane >> 4;
    const int nbase = blockIdx.x * NPB + wave * 16;

    // ---- A fragments ----
    const int na = nbase + c;
    const float f0 = frame[2 * na], f1 = frame[2 * na + 1];
    bf16x8 a0, a1, a2, a3, a4;
    {
#pragma unroll
        for (int j = 0; j < 8; ++j) {
            int k = g4 * 8 + j;
            float v = fmaf(f1, Wdy[2 * k + 1], fmaf(f0, Wdy[2 * k], bdy[k]));
            a0[j] = (short)f2b(fmaxf(v, 0.f));
        }
        a1 = *(const bf16x8*)(ghb + na * 64 + g4 * 8);
        a2 = *(const bf16x8*)(ghb + na * 64 + 32 + g4 * 8);
        a3 = *(const bf16x8*)(chb + na * 64 + g4 * 8);
        a4 = *(const bf16x8*)(chb + na * 64 + 32 + g4 * 8);
    }

    float po[4][OUTx];
#pragma unroll
    for (int r = 0; r < 4; ++r)
#pragma unroll
        for (int o = 0; o < OUTx; ++o) po[r][o] = 0.f;

#pragma unroll
    for (int q = 0; q < 4; ++q) {
        f32x4 acc[4];
#pragma unroll
        for (int g = 0; g < 4; ++g) {
            acc[g] = (f32x4){0.f, 0.f, 0.f, 0.f};
            const int colb = 16 * (4 * g + q);
            const ushort* wp = Wc + (colb + c) * KC + g4 * 8;
            bf16x8 b0 = *(const bf16x8*)(wp);
            bf16x8 b1 = *(const bf16x8*)(wp + 32);
            bf16x8 b2 = *(const bf16x8*)(wp + 64);
            bf16x8 b3 = *(const bf16x8*)(wp + 96);
            bf16x8 b4 = *(const bf16x8*)(wp + 128);
            acc[g] = __builtin_amdgcn_mfma_f32_16x16x32_bf16(a0, b0, acc[g], 0, 0, 0);
            acc[g] = __builtin_amdgcn_mfma_f32_16x16x32_bf16(a1, b1, acc[g], 0, 0, 0);
            acc[g] = __builtin_amdgcn_mfma_f32_16x16x32_bf16(a2, b2, acc[g], 0, 0, 0);
            acc[g] = __builtin_amdgcn_mfma_f32_16x16x32_bf16(a3, b3, acc[g], 0, 0, 0);
            acc[g] = __builtin_amdgcn_mfma_f32_16x16x32_bf16(a4, b4, acc[g], 0, 0, 0);
        }
        const int d = 16 * q + c;
        const float bi = bias_c[d], bf = bias_c[64 + d],
                    bg = bias_c[128 + d], bov = bias_c[192 + d];
        const float w0 = Wout[0 * 64 + d], w1 = Wout[1 * 64 + d],
                    w2 = Wout[2 * 64 + d], w3 = Wout[3 * 64 + d],
                    w4 = Wout[4 * 64 + d];
#pragma unroll
        for (int r = 0; r < 4; ++r) {
            const int n = nbase + 4 * g4 + r;
            const float ai = acc[0][r] + bi, af = acc[1][r] + bf,
                        ag = acc[2][r] + bg, ao = acc[3][r] + bov;
            const float cp = cc[n * 64 + d];
            const float c2 = fmaf(sigm(af), cp, sigm(ai) * tanh_fast(ag));
            cc[n * 64 + d] = c2;
            const float h2 = sigm(ao) * tanh_fast(c2);
            chb[n * 64 + d] = f2b(h2);
            if (last) chf[n * 64 + d] = h2;
            po[r][0] = fmaf(h2, w0, po[r][0]);
            po[r][1] = fmaf(h2, w1, po[r][1]);
            po[r][2] = fmaf(h2, w2, po[r][2]);
            po[r][3] = fmaf(h2, w3, po[r][3]);
            po[r][4] = fmaf(h2, w4, po[r][4]);
        }
    }
    // reduce over c (dims) within each g4 group; lane c==0 stores
#pragma unroll
    for (int r = 0; r < 4; ++r)
#pragma unroll
        for (int o = 0; o < OUTx; ++o) {
            float v = po[r][o];
            v += __shfl_xor(v, 1);
            v += __shfl_xor(v, 2);
            v += __shfl_xor(v, 4);
            v += __shfl_xor(v, 8);
            if (c == 0) outp[(nbase + 4 * g4 + r) * OUTx + o] = v + bo5[o];
        }
}

extern "C" void kernel_launch(void* const* d_in, const int* in_sizes, int n_in,
                              void* d_out, int out_size, void* d_ws, size_t ws_size,
                              hipStream_t stream) {
    const float* input   = (const float*)d_in[0];   // [S][N][2]
    const float* cell_h0 = (const float*)d_in[1];
    const float* cell_c0 = (const float*)d_in[2];
    const float* graph_h0= (const float*)d_in[3];
    const float* graph_c0= (const float*)d_in[4];
    const float* W_dyn   = (const float*)d_in[5];
    const float* b_dyn   = (const float*)d_in[6];
    const float* W_gemb  = (const float*)d_in[7];
    const float* b_gemb  = (const float*)d_in[8];
    const float* Wih_g   = (const float*)d_in[9];
    const float* Whh_g   = (const float*)d_in[10];
    const float* bih_g   = (const float*)d_in[11];
    const float* bhh_g   = (const float*)d_in[12];
    const float* w_graph = (const float*)d_in[13];
    const float* Wih_c   = (const float*)d_in[14];
    const float* Whh_c   = (const float*)d_in[15];
    const float* bih_c   = (const float*)d_in[16];
    const float* bhh_c   = (const float*)d_in[17];
    const float* W_out   = (const float*)d_in[18];
    const float* b_out   = (const float*)d_in[19];

    float* out0 = (float*)d_out;                        // [S][N][5]
    float* chf = out0 + (size_t)Sx * Nx * OUTx;         // [N][64] final ch
    float* cc  = chf + (size_t)Nx * CHx;                // [N][64] live cc
    float* ghf = cc  + (size_t)Nx * CHx;                // [N][64] final gh
    float* gc  = ghf + (size_t)Nx * GHx;                // [N][64] live gc

    char* w = (char*)d_ws;
    ushort* ghb     = (ushort*)w;                 w += (size_t)Nx * 64 * 2;   // 8 MB
    ushort* chb     = (ushort*)w;                 w += (size_t)Nx * 64 * 2;   // 8 MB
    float*  partials= (float*)w;                  w += (size_t)GB * 64 * 4;   // 256 KB
    ushort* Wg      = (ushort*)w;                 w += 256 * KG * 2;
    ushort* Wc      = (ushort*)w;                 w += 256 * KC * 2;
    float*  bsum_g  = (float*)w;                  w += 256 * 4;
    float*  bC0     = (float*)w;                  w += 256 * 4;
    float*  bias_c  = (float*)w;                  w += 256 * 4;

    hipMemcpyAsync(gc, graph_c0, (size_t)Nx * GHx * sizeof(float), hipMemcpyDeviceToDevice, stream);
    hipMemcpyAsync(cc, cell_c0,  (size_t)Nx * CHx * sizeof(float), hipMemcpyDeviceToDevice, stream);

    k_prep<<<1, 256, 0, stream>>>(Wih_g, Whh_g, bih_g, bhh_g, w_graph,
                                  Wih_c, Whh_c, bih_c, bhh_c,
                                  Wg, Wc, bsum_g, bC0);
    k_init<<<(Nx * 64) / 256, 256, 0, stream>>>(graph_h0, cell_h0, ghb, chb);

    for (int t = 0; t < Sx; ++t) {
        const float* frame = input + (size_t)t * Nx * 2;
        const int last = (t == Sx - 1);
        k_graph<<<GB, 256, 0, stream>>>(frame, W_gemb, b_gemb, Wg, bsum_g,
                                        gc, ghb, ghf, partials, last);
        k_reduce<<<1, 256, 0, stream>>>(partials, w_graph, Wih_c, bC0, bias_c);
        k_cell<<<GB, 256, 0, stream>>>(frame, W_dyn, b_dyn, Wc, bias_c, ghb,
                                       cc, chb, chf, W_out, b_out,
                                       out0 + (size_t)t * Nx * OUTx, last);
    }
}